// Round 15
// baseline (574.157 us; speedup 1.0000x reference)
//
#include <hip/hip_runtime.h>
#include <hip/hip_fp16.h>

#define D    300
#define DC   75    // valid D/4 chunks per row
#define PNL  8     // panels (one per XCD)
#define PCH  10    // chunks per panel per row (80 chunks total, 75 valid)
#define SCB  1024  // scan block size

typedef _Float16 half4v __attribute__((ext_vector_type(4)));

// ---------------- embedding -> fp16 h0, panel-major [PNL][N][PCH] ----------------
// grid swizzled: panel = bid & 7 (XCD round-robin) -> pre-warms panel XCD's L2.
__global__ __launch_bounds__(256) void embed_panel(const int* __restrict__ x,
                                                   const float4* __restrict__ atomT,
                                                   const float4* __restrict__ wordT,
                                                   half4v* __restrict__ h, int N) {
    int bid = blockIdx.x;
    int p = bid & 7;
    int chunk = (bid >> 3) * 256 + threadIdx.x;     // chunk within panel
    if (chunk >= N * PCH) return;
    int n = chunk / PCH, cc = chunk - n * PCH;
    int c_lin = p * PCH + cc;
    half4v o = (half4v)(_Float16)0;
    if (c_lin < DC) {
        int a = x[n * 2 + 0];
        int w = x[n * 2 + 1];
        float4 va = atomT[(size_t)a * DC + c_lin];
        float4 vw = wordT[(size_t)w * DC + c_lin];
        o[0] = (_Float16)(va.x + vw.x);
        o[1] = (_Float16)(va.y + vw.y);
        o[2] = (_Float16)(va.z + vw.z);
        o[3] = (_Float16)(va.w + vw.w);
    }
    h[(size_t)p * N * PCH + chunk] = o;
}

// ---------------- CSR build ----------------
__global__ __launch_bounds__(256) void cnt_kernel(const int* __restrict__ dst, int* __restrict__ cnt, int E) {
    int i = blockIdx.x * blockDim.x + threadIdx.x;
    if (i < E) atomicAdd(&cnt[dst[i]], 1);
}
__global__ __launch_bounds__(SCB) void scan1_kernel(const int* __restrict__ cnt,
                                                    int* __restrict__ off, int* __restrict__ bsum,
                                                    float* __restrict__ dinv, int N) {
    __shared__ int warp_sums[16];
    const int tid = threadIdx.x;
    const int lane = tid & 63;
    const int wid = tid >> 6;
    int i = blockIdx.x * SCB + tid;
    int v = (i < N) ? cnt[i] : 0;
    if (i < N) dinv[i] = rsqrtf((float)(v + 1));   // +1 self-loop
    int s = v;
    #pragma unroll
    for (int d = 1; d < 64; d <<= 1) {
        int t = __shfl_up(s, d, 64);
        if (lane >= d) s += t;
    }
    if (lane == 63) warp_sums[wid] = s;
    __syncthreads();
    if (wid == 0) {
        int ws = (lane < 16) ? warp_sums[lane] : 0;
        #pragma unroll
        for (int d = 1; d < 16; d <<= 1) {
            int t = __shfl_up(ws, d, 64);
            if (lane >= d) ws += t;
        }
        if (lane < 16) warp_sums[lane] = ws;
    }
    __syncthreads();
    int excl = (wid ? warp_sums[wid - 1] : 0) + s - v;
    if (i < N) off[i] = excl;
    if (tid == SCB - 1) bsum[blockIdx.x] = warp_sums[15];
}
__global__ __launch_bounds__(SCB) void scan2_kernel(int* __restrict__ bsum, int* __restrict__ bbase,
                                                    int* __restrict__ off, int nb, int N, int E) {
    __shared__ int warp_sums[16];
    const int tid = threadIdx.x;
    const int lane = tid & 63;
    const int wid = tid >> 6;
    int v = (tid < nb) ? bsum[tid] : 0;
    int s = v;
    #pragma unroll
    for (int d = 1; d < 64; d <<= 1) {
        int t = __shfl_up(s, d, 64);
        if (lane >= d) s += t;
    }
    if (lane == 63) warp_sums[wid] = s;
    __syncthreads();
    if (wid == 0) {
        int ws = (lane < 16) ? warp_sums[lane] : 0;
        #pragma unroll
        for (int d = 1; d < 16; d <<= 1) {
            int t = __shfl_up(ws, d, 64);
            if (lane >= d) ws += t;
        }
        if (lane < 16) warp_sums[lane] = ws;
    }
    __syncthreads();
    if (tid < nb) bbase[tid] = (wid ? warp_sums[wid - 1] : 0) + s - v;
    if (tid == 0) off[N] = E;   // sum of cnt == E identically
}
__global__ __launch_bounds__(256) void scan3_kernel(int* __restrict__ off, const int* __restrict__ bbase,
                                                    int* __restrict__ cursor, int N) {
    int i = blockIdx.x * blockDim.x + threadIdx.x;
    if (i >= N) return;
    int o = off[i] + bbase[i >> 10];
    off[i] = o;
    cursor[i] = o;
}
__global__ __launch_bounds__(256) void fill_kernel(const int* __restrict__ src, const int* __restrict__ dst,
                                                   const float* __restrict__ dinv, int* __restrict__ cursor,
                                                   int* __restrict__ csr_src, float* __restrict__ csr_w, int E) {
    int e = blockIdx.x * blockDim.x + threadIdx.x;
    if (e >= E) return;
    int s = src[e], d = dst[e];
    int slot = atomicAdd(&cursor[d], 1);
    csr_src[slot] = s;
    csr_w[slot] = dinv[s] * dinv[d];
}
__global__ __launch_bounds__(256) void seg_start_kernel(const int* __restrict__ batch,
                                                        int* __restrict__ start, int N, int G) {
    int i = blockIdx.x * blockDim.x + threadIdx.x;
    if (i >= N) return;
    int b = batch[i];
    int prev = (i == 0) ? -1 : batch[i - 1];
    for (int g = prev + 1; g <= b; ++g) start[g] = i;
    if (i == N - 1)
        for (int g = b + 1; g <= G; ++g) start[g] = N;
}

// ---------------- W-prep (2 kernels, fp32) ----------------
__global__ __launch_bounds__(256) void wprep1(const float* __restrict__ W, const float* __restrict__ bias,
                                              float* __restrict__ W2, float* __restrict__ w1b) {
    int bid = blockIdx.x;
    if (bid < 352) {
        int id = bid * 256 + threadIdx.x;
        if (id >= D * D) return;
        int i = id / D, j = id % D;
        float acc = 0.f;
        #pragma unroll 4
        for (int k = 0; k < D; ++k) acc = fmaf(W[i * D + k], W[k * D + j], acc);
        W2[id] = acc;
    } else {
        int j = threadIdx.x;
        if (j >= D) return;
        float acc = 0.f;
        #pragma unroll 4
        for (int k = 0; k < D; ++k) acc = fmaf(bias[k], W[k * D + j], acc);
        w1b[j] = acc;
    }
}
__global__ __launch_bounds__(256) void wprep2(const float* __restrict__ W2, const float* __restrict__ W,
                                              const float* __restrict__ w1b,
                                              float* __restrict__ W4, float* __restrict__ w2b,
                                              float* __restrict__ w3b) {
    int bid = blockIdx.x;
    if (bid < 352) {
        int id = bid * 256 + threadIdx.x;
        if (id >= D * D) return;
        int i = id / D, j = id % D;
        float acc = 0.f;
        #pragma unroll 4
        for (int k = 0; k < D; ++k) acc = fmaf(W2[i * D + k], W2[k * D + j], acc);
        W4[id] = acc;
    } else if (bid == 352) {
        int j = threadIdx.x;
        if (j >= D) return;
        float acc = 0.f;
        #pragma unroll 4
        for (int k = 0; k < D; ++k) acc = fmaf(w1b[k], W[k * D + j], acc);
        w2b[j] = acc;
    } else {
        int j = threadIdx.x;
        if (j >= D) return;
        float acc = 0.f;
        #pragma unroll 4
        for (int k = 0; k < D; ++k) acc = fmaf(w1b[k], W2[k * D + j], acc);
        w3b[j] = acc;
    }
}

// ---------------- panel gather: out = A_hat * in, panel p pinned to XCD p ----------------
// Panel = 4 MB (N x 80 B) = one XCD's L2 -> edge gathers are L2 hits.
// Edge metadata via nontemporal loads, output via nontemporal stores (don't evict panel).
__global__ __launch_bounds__(256) void gather_panel(const half4v* __restrict__ in,
                                                    const int* __restrict__ off,
                                                    const int* __restrict__ csr_src,
                                                    const float* __restrict__ csr_w,
                                                    const float* __restrict__ dinv,
                                                    const float* __restrict__ uin,
                                                    float* __restrict__ uout,
                                                    half4v* __restrict__ out, int N) {
    int bid = blockIdx.x;
    int p = bid & 7;                                 // panel == XCD (round-robin heuristic)
    int chunk = (bid >> 3) * 256 + threadIdx.x;
    if (chunk >= N * PCH) return;
    int n = chunk / PCH, cc = chunk - n * PCH;
    const half4v* pin = in + (size_t)p * N * PCH;

    float s = dinv[n]; s = s * s;
    half4v v0 = pin[chunk];
    float4 acc = make_float4(s * (float)v0[0], s * (float)v0[1], s * (float)v0[2], s * (float)v0[3]);
    const bool dou = (uout != nullptr) && (p == 0) && (cc == 0);
    float uacc = 0.f;
    if (dou) uacc = s * (uin ? uin[n] : 1.0f);

    int j0 = __builtin_nontemporal_load(&off[n]);
    int j1 = __builtin_nontemporal_load(&off[n + 1]);
    for (int j = j0; j < j1; ++j) {
        int sn = __builtin_nontemporal_load(&csr_src[j]);
        float w = __builtin_nontemporal_load(&csr_w[j]);
        half4v u = pin[(size_t)sn * PCH + cc];       // L2-resident panel row
        acc.x += w * (float)u[0]; acc.y += w * (float)u[1];
        acc.z += w * (float)u[2]; acc.w += w * (float)u[3];
        if (dou) uacc += w * (uin ? uin[sn] : 1.0f);
    }
    half4v o;
    o[0] = (_Float16)acc.x; o[1] = (_Float16)acc.y;
    o[2] = (_Float16)acc.z; o[3] = (_Float16)acc.w;
    __builtin_nontemporal_store(o, &out[(size_t)p * N * PCH + chunk]);
    if (dou) uout[n] = uacc;
}

// ---------------- pool g4 + u's per graph (panel-major input) ----------------
__global__ __launch_bounds__(256) void pool_seg(const half4v* __restrict__ g4,
                                                const float* __restrict__ u1,
                                                const float* __restrict__ u2,
                                                const float* __restrict__ u3,
                                                const int* __restrict__ start,
                                                float* __restrict__ pg4, float* __restrict__ pu,
                                                int G, int N) {
    int g = blockIdx.x;
    if (g >= G) return;
    int j0 = start[g], j1 = start[g + 1];
    float inv = (j1 > j0) ? 1.0f / (float)(j1 - j0) : 0.0f;
    int tid = threadIdx.x;
    if (tid < PNL * PCH) {
        int p = tid / PCH, cc = tid - p * PCH;
        int c_lin = p * PCH + cc;
        if (c_lin < DC) {
            const half4v* pg = g4 + (size_t)p * N * PCH;
            float4 acc = make_float4(0.f, 0.f, 0.f, 0.f);
            for (int n = j0; n < j1; ++n) {
                half4v v = pg[(size_t)n * PCH + cc];
                acc.x += (float)v[0]; acc.y += (float)v[1];
                acc.z += (float)v[2]; acc.w += (float)v[3];
            }
            float4 o = make_float4(acc.x * inv, acc.y * inv, acc.z * inv, acc.w * inv);
            *(float4*)&pg4[(size_t)g * D + c_lin * 4] = o;
        }
    } else if (tid >= 80 && tid <= 82) {
        const float* u = (tid == 80) ? u1 : (tid == 81) ? u2 : u3;
        float acc = 0.f;
        for (int n = j0; n < j1; ++n) acc += u[n];
        pu[g * 4 + (tid - 80)] = acc * inv;
    } else if (tid == 83) {
        pu[g * 4 + 3] = (j1 > j0) ? 1.0f : 0.0f;
    }
}

// ---------------- final small GEMM (fp32, exact): out = pg4@W4 + rank-1 terms ----------------
__global__ __launch_bounds__(256) void final_small(const float* __restrict__ pg4,
                                                   const float* __restrict__ pu,
                                                   const float* __restrict__ W4,
                                                   const float* __restrict__ w1b,
                                                   const float* __restrict__ w2b,
                                                   const float* __restrict__ w3b,
                                                   const float* __restrict__ bias,
                                                   float* __restrict__ out, int G) {
    __shared__ float row[D];
    int g = blockIdx.x;
    if (g >= G) return;
    int tid = threadIdx.x;
    for (int c = tid; c < D; c += 256) row[c] = pg4[(size_t)g * D + c];
    __syncthreads();
    float p1 = pu[g * 4 + 0], p2 = pu[g * 4 + 1], p3 = pu[g * 4 + 2], fl = pu[g * 4 + 3];
    for (int j = tid; j < D; j += 256) {
        float acc = 0.f;
        #pragma unroll 4
        for (int k = 0; k < D; ++k) acc = fmaf(row[k], W4[(size_t)k * D + j], acc);
        out[(size_t)g * D + j] = acc + p1 * w1b[j] + p2 * w2b[j] + p3 * w3b[j] + fl * bias[j];
    }
}

extern "C" void kernel_launch(void* const* d_in, const int* in_sizes, int n_in,
                              void* d_out, int out_size, void* d_ws, size_t ws_size,
                              hipStream_t stream) {
    (void)n_in; (void)ws_size;
    const int*   x     = (const int*)d_in[0];
    const int*   ei    = (const int*)d_in[1];
    const int*   batch = (const int*)d_in[2];
    // d_in[3] = num_hops (fixed 4)
    const float* atomT = (const float*)d_in[4];
    const float* wordT = (const float*)d_in[5];
    const float* W     = (const float*)d_in[6];
    const float* bias  = (const float*)d_in[7];

    const int N = in_sizes[0] / 2;
    const int E = in_sizes[1] / 2;
    const int G = out_size / D;

    const int* src = ei;
    const int* dst = ei + E;

    // workspace layout (16B-aligned starts); panel buffers are N*80 chunks of 8B = 32MB each
    _Float16* fA16   = (_Float16*)d_ws;                   // PNL*N*PCH*4 fp16
    _Float16* fB16   = fA16 + (size_t)PNL * N * PCH * 4;  // PNL*N*PCH*4 fp16
    float*    dinv   = (float*)(fB16 + (size_t)PNL * N * PCH * 4); // N
    float*    csr_w  = dinv + N;                          // E
    float*    W2     = csr_w + E;                         // D*D
    float*    W4     = W2 + D * D;                        // D*D
    float*    w1b    = W4 + D * D;                        // D
    float*    w2b    = w1b + D;                           // D
    float*    w3b    = w2b + D;                           // D
    float*    u1     = w3b + D;                           // N
    float*    u2     = u1 + N;                            // N
    float*    u3     = u2 + N;                            // N
    float*    pg4    = u3 + N;                            // G*D
    float*    pu     = pg4 + (size_t)G * D;               // 4*G
    int*      cnt    = (int*)(pu + 4 * G);                // N
    int*      off    = cnt + N;                           // N+1
    int*      cursor = off + N + 1;                       // N
    int*      csr_src= cursor + N;                        // E
    int*      bsum   = csr_src + E;                       // <=1024
    int*      bbase  = bsum + 1024;                       // <=1024
    int*      start  = bbase + 1024;                      // G+1

    const int B = 256;
    const int nBlocks  = (N + B - 1) / B;
    const int nbScan   = (N + SCB - 1) / SCB;
    const int nbPanel  = (N * PCH + B - 1) / B;           // blocks per panel
    const int panelGrid = nbPanel * PNL;                  // swizzled: panel = bid & 7

    embed_panel<<<panelGrid, B, 0, stream>>>(x, (const float4*)atomT, (const float4*)wordT,
                                             (half4v*)fA16, N);

    hipMemsetAsync(cnt, 0, (size_t)N * sizeof(int), stream);
    cnt_kernel<<<(E + B - 1) / B, B, 0, stream>>>(dst, cnt, E);
    scan1_kernel<<<nbScan, SCB, 0, stream>>>(cnt, off, bsum, dinv, N);
    scan2_kernel<<<1, SCB, 0, stream>>>(bsum, bbase, off, nbScan, N, E);
    scan3_kernel<<<nBlocks, B, 0, stream>>>(off, bbase, cursor, N);
    fill_kernel<<<(E + B - 1) / B, B, 0, stream>>>(src, dst, dinv, cursor, csr_src, csr_w, E);
    seg_start_kernel<<<nBlocks, B, 0, stream>>>(batch, start, N, G);

    wprep1<<<353, B, 0, stream>>>(W, bias, W2, w1b);
    wprep2<<<354, B, 0, stream>>>(W2, W, w1b, W4, w2b, w3b);

    // g_k = A_hat^k h0 (panel ping-pong), u_k fused into passes 1-3 (panel 0)
    gather_panel<<<panelGrid, B, 0, stream>>>((const half4v*)fA16, off, csr_src, csr_w, dinv,
                                              nullptr, u1, (half4v*)fB16, N);
    gather_panel<<<panelGrid, B, 0, stream>>>((const half4v*)fB16, off, csr_src, csr_w, dinv,
                                              u1, u2, (half4v*)fA16, N);
    gather_panel<<<panelGrid, B, 0, stream>>>((const half4v*)fA16, off, csr_src, csr_w, dinv,
                                              u2, u3, (half4v*)fB16, N);
    gather_panel<<<panelGrid, B, 0, stream>>>((const half4v*)fB16, off, csr_src, csr_w, dinv,
                                              nullptr, nullptr, (half4v*)fA16, N);

    // pool first (linear), then tiny exact-fp32 GEMM on G rows
    pool_seg<<<G, B, 0, stream>>>((const half4v*)fA16, u1, u2, u3, start, pg4, pu, G, N);
    final_small<<<G, B, 0, stream>>>(pg4, pu, W4, w1b, w2b, w3b, bias, (float*)d_out, G);
}